// Round 3
// baseline (342.109 us; speedup 1.0000x reference)
//
#include <hip/hip_runtime.h>

#define NIB_SCALE 100.0f

// ---- DPP helpers (16-lane "row" ops on the VALU pipe; rows == nibble groups) ----
// ctrl: 0x110+N row_shr, 0x120+N row_ror, 0x140 row_mirror
template<int CTRL>
__device__ __forceinline__ float fdpp(float x) {
    return __int_as_float(__builtin_amdgcn_update_dpp(
        0, __float_as_int(x), CTRL, 0xF, 0xF, true));
}

__device__ __forceinline__ float rsum16d(float v) {
    v += fdpp<0x121>(v); v += fdpp<0x122>(v); v += fdpp<0x124>(v); v += fdpp<0x128>(v);
    return v;
}
__device__ __forceinline__ float rmax16d(float v) {
    v = fmaxf(v, fdpp<0x121>(v)); v = fmaxf(v, fdpp<0x122>(v));
    v = fmaxf(v, fdpp<0x124>(v)); v = fmaxf(v, fdpp<0x128>(v));
    return v;
}
// inclusive ascending prefix sum within the 16-lane row
__device__ __forceinline__ float scan16d(float v) {
    v += fdpp<0x111>(v); v += fdpp<0x112>(v); v += fdpp<0x114>(v); v += fdpp<0x118>(v);
    return v;
}
__device__ __forceinline__ float softmax16d(float v) {
    float m = rmax16d(v);
    float e = __expf(NIB_SCALE * (v - m));
    float s = rsum16d(e);
    return e / s;
}
__device__ __forceinline__ float sharp_sigmoid(float c) {
    // softmax2(100*[1-c, c])[1] = 1/(1+exp(100*(1-2c)))
    return 1.0f / (1.0f + __expf(NIB_SCALE * (1.0f - 2.0f * c)));
}

// one quarter of the circular conv: 4-FMA chain over one float4 of Q with
// in-place rotated P values (no G[] array -> shorter chains, fewer live regs)
__device__ __forceinline__ float conv_quad(float g0, float g1, float g2, float g3,
                                           const float4 q) {
    return fmaf(g0, q.x, fmaf(g1, q.y, fmaf(g2, q.z, g3 * q.w)));
}

// serial ripple-carry chain over 4 bytes from the per-byte overflow masses;
// returns the carry mix weights for byte position b
__device__ __forceinline__ void carry_chain(const float4 O16L, const float4 O15L,
                                            const float4 O16H, const float4 O15H, int b,
                                            float& pc0, float& pc1, float& qc0, float& qc1) {
    // byte 0: incoming pc = (1, 0)  (softmax2([1,0]*100): pc1 = 3.7e-44 ~ 0)
    float qc1_0 = sharp_sigmoid(O16L.x);
    float qc0_0 = 1.f - qc1_0;
    float pc1_1 = sharp_sigmoid(qc0_0 * O16H.x + qc1_0 * O15H.x);
    float pc0_1 = 1.f - pc1_1;
    float qc1_1 = sharp_sigmoid(pc0_1 * O16L.y + pc1_1 * O15L.y);
    float qc0_1 = 1.f - qc1_1;
    float pc1_2 = sharp_sigmoid(qc0_1 * O16H.y + qc1_1 * O15H.y);
    float pc0_2 = 1.f - pc1_2;
    float qc1_2 = sharp_sigmoid(pc0_2 * O16L.z + pc1_2 * O15L.z);
    float qc0_2 = 1.f - qc1_2;
    float pc1_3 = sharp_sigmoid(qc0_2 * O16H.z + qc1_2 * O15H.z);
    float pc0_3 = 1.f - pc1_3;
    float qc1_3 = sharp_sigmoid(pc0_3 * O16L.w + pc1_3 * O15L.w);
    float qc0_3 = 1.f - qc1_3;
    // select this group's byte position (b is group-uniform -> cheap cndmasks)
    pc0 = b == 0 ? 1.f   : b == 1 ? pc0_1 : b == 2 ? pc0_2 : pc0_3;
    pc1 = b == 0 ? 0.f   : b == 1 ? pc1_1 : b == 2 ? pc1_2 : pc1_3;
    qc0 = b == 0 ? qc0_0 : b == 1 ? qc0_1 : b == 2 ? qc0_2 : qc0_3;
    qc1 = b == 0 ? qc1_0 : b == 1 ? qc1_1 : b == 2 ? qc1_2 : qc1_3;
}

// TWO rows per wave as two independent dataflow streams, phase-interleaved.
// Rationale (r0-r2 counters): wall-time tracks VALU-issue at a pinned ~27%
// utilization -> per-wave dependence chains limit issue rate, not loads, not
// occupancy. Twin streams double ILP at identical total VALU work.
__global__ __launch_bounds__(256, 4) void nalu_kernel(const float* __restrict__ A,
                                                      const float* __restrict__ B,
                                                      float* __restrict__ O,
                                                      int nrows) {
    // all cross-lane LDS traffic stays inside one wave -> no barriers needed
    __shared__ __align__(16) float sQL[2][16][16];
    __shared__ __align__(16) float sQH[2][16][16];
    __shared__ __align__(16) float sPSL[2][16][16];
    __shared__ __align__(16) float sPSH[2][16][16];
    __shared__ __align__(16) float sOV[2][4][4][4];  // [stream][wave][{o16l,o15l,o16h,o15h}][byte]

    const int tid = threadIdx.x;
    const int k = tid & 15;           // nibble-value lane within the 16-lane group
    const int g = tid >> 4;           // group id within block (16 groups)
    const int b = g & 3;              // byte index handled by this group
    const int w = tid >> 6;           // wave id within block
    const int row = blockIdx.x * 8 + w * 2;
    if (row >= nrows) return;
    const long base0 = (long)row * 1024 + b * 256;
    // tail clamp: stream 1 duplicates stream 0 (same data to same address, benign)
    const long base1 = base0 + ((row + 1 < nrows) ? 1024 : 0);

    const float* pa0 = A + base0;  const float* pb0 = B + base0;
    const float* pa1 = A + base1;  const float* pb1 = B + base1;

    // ---- b2n loads, both streams issued together (deep MLP) ----
    // low-nibble logits = column sums of the 16x16 block: strided dwords
    float uA0 = 0, uA1 = 0, uA2 = 0, uA3 = 0, uB0 = 0, uB1 = 0, uB2 = 0, uB3 = 0;
    float vA0 = 0, vA1 = 0, vA2 = 0, vA3 = 0, vB0 = 0, vB1 = 0, vB2 = 0, vB3 = 0;
    #pragma unroll
    for (int e = 0; e < 4; ++e) {
        uA0 += pa0[16 * e + k];        uB0 += pb0[16 * e + k];
        uA1 += pa0[16 * (e + 4) + k];  uB1 += pb0[16 * (e + 4) + k];
        uA2 += pa0[16 * (e + 8) + k];  uB2 += pb0[16 * (e + 8) + k];
        uA3 += pa0[16 * (e + 12) + k]; uB3 += pb0[16 * (e + 12) + k];
        vA0 += pa1[16 * e + k];        vB0 += pb1[16 * e + k];
        vA1 += pa1[16 * (e + 4) + k];  vB1 += pb1[16 * (e + 4) + k];
        vA2 += pa1[16 * (e + 8) + k];  vB2 += pb1[16 * (e + 8) + k];
        vA3 += pa1[16 * (e + 12) + k]; vB3 += pb1[16 * (e + 12) + k];
    }
    float al0 = (uA0 + uA1) + (uA2 + uA3), bl0 = (uB0 + uB1) + (uB2 + uB3);
    float al1 = (vA0 + vA1) + (vA2 + vA3), bl1 = (vB0 + vB1) + (vB2 + vB3);

    // high-nibble logits = row sums: float4 loads (same lines -> L1 hits)
    const float4* qa0 = (const float4*)(pa0 + 16 * k);
    const float4* qb0 = (const float4*)(pb0 + 16 * k);
    const float4* qa1 = (const float4*)(pa1 + 16 * k);
    const float4* qb1 = (const float4*)(pb1 + 16 * k);
    float4 t0, t1, t2, t3;
    t0 = qa0[0]; t1 = qa0[1]; t2 = qa0[2]; t3 = qa0[3];
    float ah0 = ((t0.x + t0.y) + (t0.z + t0.w)) + ((t1.x + t1.y) + (t1.z + t1.w))
              + ((t2.x + t2.y) + (t2.z + t2.w)) + ((t3.x + t3.y) + (t3.z + t3.w));
    t0 = qb0[0]; t1 = qb0[1]; t2 = qb0[2]; t3 = qb0[3];
    float bh0 = ((t0.x + t0.y) + (t0.z + t0.w)) + ((t1.x + t1.y) + (t1.z + t1.w))
              + ((t2.x + t2.y) + (t2.z + t2.w)) + ((t3.x + t3.y) + (t3.z + t3.w));
    t0 = qa1[0]; t1 = qa1[1]; t2 = qa1[2]; t3 = qa1[3];
    float ah1 = ((t0.x + t0.y) + (t0.z + t0.w)) + ((t1.x + t1.y) + (t1.z + t1.w))
              + ((t2.x + t2.y) + (t2.z + t2.w)) + ((t3.x + t3.y) + (t3.z + t3.w));
    t0 = qb1[0]; t1 = qb1[1]; t2 = qb1[2]; t3 = qb1[3];
    float bh1 = ((t0.x + t0.y) + (t0.z + t0.w)) + ((t1.x + t1.y) + (t1.z + t1.w))
              + ((t2.x + t2.y) + (t2.z + t2.w)) + ((t3.x + t3.y) + (t3.z + t3.w));

    // ---- factorized sharp softmaxes, 8 independent reductions interleaved ----
    float pal0 = softmax16d(al0);  float pal1 = softmax16d(al1);
    float pbl0 = softmax16d(bl0);  float pbl1 = softmax16d(bl1);
    float pah0 = softmax16d(ah0);  float pah1 = softmax16d(ah1);
    float pbh0 = softmax16d(bh0);  float pbh1 = softmax16d(bh1);

    sQL[0][g][k] = pbl0;  sQL[1][g][k] = pbl1;
    sQH[0][g][k] = pbh0;  sQH[1][g][k] = pbh1;

    // ---- overflow masses, pure DPP, both streams ----
    float mirl0 = fdpp<0x140>(pbl0);  float mirl1 = fdpp<0x140>(pbl1);
    float mirh0 = fdpp<0x140>(pbh0);  float mirh1 = fdpp<0x140>(pbh1);
    float T15l0 = scan16d(mirl0);     float T15l1 = scan16d(mirl1);
    float T15h0 = scan16d(mirh0);     float T15h1 = scan16d(mirh1);
    float ov15l0 = rsum16d(pal0 * T15l0);  float ov15l1 = rsum16d(pal1 * T15l1);
    float c15l0  = rsum16d(pal0 * mirl0);  float c15l1  = rsum16d(pal1 * mirl1);
    float ov15h0 = rsum16d(pah0 * T15h0);  float ov15h1 = rsum16d(pah1 * T15h1);
    float c15h0  = rsum16d(pah0 * mirh0);  float c15h1  = rsum16d(pah1 * mirh1);

    sOV[0][w][0][b] = ov15l0 - c15l0;   sOV[1][w][0][b] = ov15l1 - c15l1;
    sOV[0][w][1][b] = ov15l0;           sOV[1][w][1][b] = ov15l1;
    sOV[0][w][2][b] = ov15h0 - c15h0;   sOV[1][w][2][b] = ov15h1 - c15h1;
    sOV[0][w][3][b] = ov15h0;           sOV[1][w][3][b] = ov15h1;

    // ---- circular convolutions r[k] = sum_j p[(k-j)&15] q[j] ----
    // tree of four 4-FMA chains per conv; rotated P consumed in place
    const float4 L0a = *(const float4*)&sQL[0][g][0];
    const float4 L0b = *(const float4*)&sQL[0][g][4];
    const float4 L0c = *(const float4*)&sQL[0][g][8];
    const float4 L0d = *(const float4*)&sQL[0][g][12];
    const float4 L1a = *(const float4*)&sQL[1][g][0];
    const float4 L1b = *(const float4*)&sQL[1][g][4];
    const float4 L1c = *(const float4*)&sQL[1][g][8];
    const float4 L1d = *(const float4*)&sQL[1][g][12];
    float rl0 = (conv_quad(pal0,               fdpp<0x121>(pal0), fdpp<0x122>(pal0), fdpp<0x123>(pal0), L0a)
               + conv_quad(fdpp<0x124>(pal0), fdpp<0x125>(pal0), fdpp<0x126>(pal0), fdpp<0x127>(pal0), L0b))
              + (conv_quad(fdpp<0x128>(pal0), fdpp<0x129>(pal0), fdpp<0x12A>(pal0), fdpp<0x12B>(pal0), L0c)
               + conv_quad(fdpp<0x12C>(pal0), fdpp<0x12D>(pal0), fdpp<0x12E>(pal0), fdpp<0x12F>(pal0), L0d));
    float rl1 = (conv_quad(pal1,               fdpp<0x121>(pal1), fdpp<0x122>(pal1), fdpp<0x123>(pal1), L1a)
               + conv_quad(fdpp<0x124>(pal1), fdpp<0x125>(pal1), fdpp<0x126>(pal1), fdpp<0x127>(pal1), L1b))
              + (conv_quad(fdpp<0x128>(pal1), fdpp<0x129>(pal1), fdpp<0x12A>(pal1), fdpp<0x12B>(pal1), L1c)
               + conv_quad(fdpp<0x12C>(pal1), fdpp<0x12D>(pal1), fdpp<0x12E>(pal1), fdpp<0x12F>(pal1), L1d));

    const float4 H0a = *(const float4*)&sQH[0][g][0];
    const float4 H0b = *(const float4*)&sQH[0][g][4];
    const float4 H0c = *(const float4*)&sQH[0][g][8];
    const float4 H0d = *(const float4*)&sQH[0][g][12];
    const float4 H1a = *(const float4*)&sQH[1][g][0];
    const float4 H1b = *(const float4*)&sQH[1][g][4];
    const float4 H1c = *(const float4*)&sQH[1][g][8];
    const float4 H1d = *(const float4*)&sQH[1][g][12];
    float rh0 = (conv_quad(pah0,               fdpp<0x121>(pah0), fdpp<0x122>(pah0), fdpp<0x123>(pah0), H0a)
               + conv_quad(fdpp<0x124>(pah0), fdpp<0x125>(pah0), fdpp<0x126>(pah0), fdpp<0x127>(pah0), H0b))
              + (conv_quad(fdpp<0x128>(pah0), fdpp<0x129>(pah0), fdpp<0x12A>(pah0), fdpp<0x12B>(pah0), H0c)
               + conv_quad(fdpp<0x12C>(pah0), fdpp<0x12D>(pah0), fdpp<0x12E>(pah0), fdpp<0x12F>(pah0), H0d));
    float rh1 = (conv_quad(pah1,               fdpp<0x121>(pah1), fdpp<0x122>(pah1), fdpp<0x123>(pah1), H1a)
               + conv_quad(fdpp<0x124>(pah1), fdpp<0x125>(pah1), fdpp<0x126>(pah1), fdpp<0x127>(pah1), H1b))
              + (conv_quad(fdpp<0x128>(pah1), fdpp<0x129>(pah1), fdpp<0x12A>(pah1), fdpp<0x12B>(pah1), H1c)
               + conv_quad(fdpp<0x12C>(pah1), fdpp<0x12D>(pah1), fdpp<0x12E>(pah1), fdpp<0x12F>(pah1), H1d));

    // ---- serial carry chains (tiny; redundant per lane; twin chains overlap) ----
    float pc0_0, pc1_0, qc0_0, qc1_0, pc0_1, pc1_1, qc0_1, qc1_1;
    carry_chain(*(const float4*)&sOV[0][w][0][0], *(const float4*)&sOV[0][w][1][0],
                *(const float4*)&sOV[0][w][2][0], *(const float4*)&sOV[0][w][3][0],
                b, pc0_0, pc1_0, qc0_0, qc1_0);
    carry_chain(*(const float4*)&sOV[1][w][0][0], *(const float4*)&sOV[1][w][1][0],
                *(const float4*)&sOV[1][w][2][0], *(const float4*)&sOV[1][w][3][0],
                b, pc0_1, pc1_1, qc0_1, qc1_1);

    // ---- nibble sums with carry mixing ----
    float slow0  = pc0_0 * rl0 + pc1_0 * fdpp<0x121>(rl0);   // rl[(k-1)&15]
    float slow1  = pc0_1 * rl1 + pc1_1 * fdpp<0x121>(rl1);
    float shigh0 = qc0_0 * rh0 + qc1_0 * fdpp<0x121>(rh0);
    float shigh1 = qc0_1 * rh1 + qc1_1 * fdpp<0x121>(rh1);

    // ---- n2b: out[16h + l] = psh[h] * psl[l] ----
    float psl0 = softmax16d(slow0);   float psl1 = softmax16d(slow1);
    float psh0 = softmax16d(shigh0);  float psh1 = softmax16d(shigh1);
    sPSL[0][g][k] = psl0;  sPSL[1][g][k] = psl1;
    sPSH[0][g][k] = psh0;  sPSH[1][g][k] = psh1;

    // full-cache-line stores: instr c writes group's bytes [64c .. 64c+63]
    const float4 pq0 = *(const float4*)&sPSL[0][g][4 * (k & 3)];
    const float4 pq1 = *(const float4*)&sPSL[1][g][4 * (k & 3)];
    float* po0 = O + base0;
    float* po1 = O + base1;
    #pragma unroll
    for (int c = 0; c < 4; ++c) {
        float hs0 = sPSH[0][g][4 * c + (k >> 2)];
        float hs1 = sPSH[1][g][4 * c + (k >> 2)];
        *(float4*)(po0 + 64 * c + 4 * k) = make_float4(hs0 * pq0.x, hs0 * pq0.y, hs0 * pq0.z, hs0 * pq0.w);
        *(float4*)(po1 + 64 * c + 4 * k) = make_float4(hs1 * pq1.x, hs1 * pq1.y, hs1 * pq1.z, hs1 * pq1.w);
    }
}

extern "C" void kernel_launch(void* const* d_in, const int* in_sizes, int n_in,
                              void* d_out, int out_size, void* d_ws, size_t ws_size,
                              hipStream_t stream) {
    const float* A = (const float*)d_in[0];
    const float* B = (const float*)d_in[1];
    float* O = (float*)d_out;
    int nrows = in_sizes[0] / 1024;          // [B,4,256] -> B
    int grid = (nrows + 7) / 8;              // 8 rows per block: 4 waves x 2 streams
    nalu_kernel<<<grid, 256, 0, stream>>>(A, B, O, nrows);
}

// Round 4
// 315.066 us; speedup vs baseline: 1.0858x; 1.0858x over previous
//
#include <hip/hip_runtime.h>

#define NIB_SCALE 100.0f

// ---- DPP helpers (16-lane "row" ops on the VALU pipe; rows == nibble groups) ----
// ctrl: 0x110+N row_shr, 0x120+N row_ror, 0x140 row_mirror
template<int CTRL>
__device__ __forceinline__ float fdpp(float x) {
    return __int_as_float(__builtin_amdgcn_update_dpp(
        0, __float_as_int(x), CTRL, 0xF, 0xF, true));
}

__device__ __forceinline__ float rsum16d(float v) {
    v += fdpp<0x121>(v); v += fdpp<0x122>(v); v += fdpp<0x124>(v); v += fdpp<0x128>(v);
    return v;
}
__device__ __forceinline__ float rmax16d(float v) {
    v = fmaxf(v, fdpp<0x121>(v)); v = fmaxf(v, fdpp<0x122>(v));
    v = fmaxf(v, fdpp<0x124>(v)); v = fmaxf(v, fdpp<0x128>(v));
    return v;
}
// inclusive ascending prefix sum within the 16-lane row
__device__ __forceinline__ float scan16d(float v) {
    v += fdpp<0x111>(v); v += fdpp<0x112>(v); v += fdpp<0x114>(v); v += fdpp<0x118>(v);
    return v;
}
__device__ __forceinline__ float softmax16d(float v) {
    float m = rmax16d(v);
    float e = __expf(NIB_SCALE * (v - m));
    float s = rsum16d(e);
    return e / s;
}
__device__ __forceinline__ float sharp_sigmoid(float c) {
    // softmax2(100*[1-c, c])[1] = 1/(1+exp(100*(1-2c)))
    return 1.0f / (1.0f + __expf(NIB_SCALE * (1.0f - 2.0f * c)));
}

// one quarter of the circular conv: 4-FMA chain over one float4 of Q with
// in-place rotated P values (no G[] array -> shorter chains, fewer live regs)
__device__ __forceinline__ float conv_quad(float g0, float g1, float g2, float g3,
                                           const float4 q) {
    return fmaf(g0, q.x, fmaf(g1, q.y, fmaf(g2, q.z, g3 * q.w)));
}

// column sums from row-resident float4 data: per-component 16-lane reduction
// (row-uniform result), then lane k selects column k = chunk k>>2, comp k&3.
// Replaces 16 strided global dword loads per input with pure-VALU DPP work
// (issue port is ~73% idle; the strided loads were occupying MSHRs).
#define COLSUM_CHUNK(dst, r4, c)                                  \
    {                                                             \
        float s0 = rsum16d(r4.x), s1 = rsum16d(r4.y);             \
        float s2 = rsum16d(r4.z), s3 = rsum16d(r4.w);             \
        float t0 = (k & 1) ? s1 : s0;                             \
        float t1 = (k & 1) ? s3 : s2;                             \
        float tc = (k & 2) ? t1 : t0;                             \
        dst = ((k >> 2) == (c)) ? tc : dst;                       \
    }

// serial ripple-carry chain over 4 bytes from the per-byte overflow masses;
// returns the carry mix weights for byte position b
__device__ __forceinline__ void carry_chain(const float4 O16L, const float4 O15L,
                                            const float4 O16H, const float4 O15H, int b,
                                            float& pc0, float& pc1, float& qc0, float& qc1) {
    // byte 0: incoming pc = (1, 0)  (softmax2([1,0]*100): pc1 = 3.7e-44 ~ 0)
    float qc1_0 = sharp_sigmoid(O16L.x);
    float qc0_0 = 1.f - qc1_0;
    float pc1_1 = sharp_sigmoid(qc0_0 * O16H.x + qc1_0 * O15H.x);
    float pc0_1 = 1.f - pc1_1;
    float qc1_1 = sharp_sigmoid(pc0_1 * O16L.y + pc1_1 * O15L.y);
    float qc0_1 = 1.f - qc1_1;
    float pc1_2 = sharp_sigmoid(qc0_1 * O16H.y + qc1_1 * O15H.y);
    float pc0_2 = 1.f - pc1_2;
    float qc1_2 = sharp_sigmoid(pc0_2 * O16L.z + pc1_2 * O15L.z);
    float qc0_2 = 1.f - qc1_2;
    float pc1_3 = sharp_sigmoid(qc0_2 * O16H.z + qc1_2 * O15H.z);
    float pc0_3 = 1.f - pc1_3;
    float qc1_3 = sharp_sigmoid(pc0_3 * O16L.w + pc1_3 * O15L.w);
    float qc0_3 = 1.f - qc1_3;
    // select this group's byte position (b is group-uniform -> cheap cndmasks)
    pc0 = b == 0 ? 1.f   : b == 1 ? pc0_1 : b == 2 ? pc0_2 : pc0_3;
    pc1 = b == 0 ? 0.f   : b == 1 ? pc1_1 : b == 2 ? pc1_2 : pc1_3;
    qc0 = b == 0 ? qc0_0 : b == 1 ? qc0_1 : b == 2 ? qc0_2 : qc0_3;
    qc1 = b == 0 ? qc1_0 : b == 1 ? qc1_1 : b == 2 ? qc1_2 : qc1_3;
}

// One wave = one 4-byte row per iteration, 4 consecutive rows per wave.
// 2-deep register pipeline: next row's 8 float4 loads are issued at the top of
// each iteration and pinned above the compute tail by sched_barrier(0), so
// ~128 cache lines stay outstanding under the ~2000-cycle tail (r0-r3 showed
// the kernel is bound by outstanding-request duty cycle, not BW or VALU).
__global__ void nalu_kernel(const float* __restrict__ A,
                            const float* __restrict__ B,
                            float* __restrict__ O,
                            int nrows) {
    // all cross-lane LDS traffic stays inside one wave -> no barriers needed
    __shared__ __align__(16) float sQL[16][16];
    __shared__ __align__(16) float sQH[16][16];
    __shared__ __align__(16) float sPSL[16][16];
    __shared__ __align__(16) float sPSH[16][16];
    __shared__ __align__(16) float sOV[4][4][4];  // [wave][{o16l,o15l,o16h,o15h}][byte]

    const int tid = threadIdx.x;
    const int k = tid & 15;           // nibble-value lane within the 16-lane group
    const int g = tid >> 4;           // group id within block (16 groups)
    const int b = g & 3;              // byte index handled by this group
    const int w = tid >> 6;           // wave id within block
    constexpr int ROWS = 4;           // rows per wave (pipeline length)
    const int row0 = blockIdx.x * (4 * ROWS) + w * ROWS;
    if (row0 >= nrows) return;
    long base = (long)row0 * 1024 + b * 256;

    // ---- prologue: first row's loads in flight ----
    const float4* pa4 = (const float4*)(A + base + 16 * k);
    const float4* pb4 = (const float4*)(B + base + 16 * k);
    float4 ra0 = pa4[0], ra1 = pa4[1], ra2 = pa4[2], ra3 = pa4[3];
    float4 rb0 = pb4[0], rb1 = pb4[1], rb2 = pb4[2], rb3 = pb4[3];

    #pragma unroll
    for (int i = 0; i < ROWS; ++i) {
        if (row0 + i >= nrows) break;                 // wave-uniform
        const bool more = (i + 1 < ROWS) && (row0 + i + 1 < nrows);
        const long nbase = more ? base + 1024 : base; // clamp: harmless reload

        // ---- issue next row's loads FIRST (counted-wait friendly) ----
        const float4* na4 = (const float4*)(A + nbase + 16 * k);
        const float4* nb4 = (const float4*)(B + nbase + 16 * k);
        float4 xa0 = na4[0], xa1 = na4[1], xa2 = na4[2], xa3 = na4[3];
        float4 xb0 = nb4[0], xb1 = nb4[1], xb2 = nb4[2], xb3 = nb4[3];

        // ---- consume current row: logits only ----
        // high-nibble logits = row sums (lane-local)
        float ah = ((ra0.x + ra0.y) + (ra0.z + ra0.w)) + ((ra1.x + ra1.y) + (ra1.z + ra1.w))
                 + ((ra2.x + ra2.y) + (ra2.z + ra2.w)) + ((ra3.x + ra3.y) + (ra3.z + ra3.w));
        float bh = ((rb0.x + rb0.y) + (rb0.z + rb0.w)) + ((rb1.x + rb1.y) + (rb1.z + rb1.w))
                 + ((rb2.x + rb2.y) + (rb2.z + rb2.w)) + ((rb3.x + rb3.y) + (rb3.z + rb3.w));
        // low-nibble logits = column sums via DPP reductions
        float al = 0.f, bl = 0.f;
        COLSUM_CHUNK(al, ra0, 0) COLSUM_CHUNK(al, ra1, 1)
        COLSUM_CHUNK(al, ra2, 2) COLSUM_CHUNK(al, ra3, 3)
        COLSUM_CHUNK(bl, rb0, 0) COLSUM_CHUNK(bl, rb1, 1)
        COLSUM_CHUNK(bl, rb2, 2) COLSUM_CHUNK(bl, rb3, 3)

        // ---- fence: next-row loads may not sink below this point ----
        __builtin_amdgcn_sched_barrier(0);

        // ---- factorized sharp softmaxes (exact vs the joint 512-softmax) ----
        float pal = softmax16d(al);
        float pbl = softmax16d(bl);
        float pah = softmax16d(ah);
        float pbh = softmax16d(bh);

        sQL[g][k] = pbl;
        sQH[g][k] = pbh;

        // overflow masses, pure DPP:
        // mir[k]=q[15-k]; T15[k]=sum_{v>=15-k} q[v]; ov15=sum_{a+v>=15} p[a]q[v]
        float mirl = fdpp<0x140>(pbl);
        float mirh = fdpp<0x140>(pbh);
        float T15l = scan16d(mirl);
        float T15h = scan16d(mirh);
        float ov15l = rsum16d(pal * T15l);
        float c15l  = rsum16d(pal * mirl);
        float ov15h = rsum16d(pah * T15h);
        float c15h  = rsum16d(pah * mirh);

        // publish per-byte carry constants (uniform within group; benign dup writes)
        sOV[w][0][b] = ov15l - c15l;   // ov16l
        sOV[w][1][b] = ov15l;
        sOV[w][2][b] = ov15h - c15h;   // ov16h
        sOV[w][3][b] = ov15h;

        // ---- circular convolutions r[k] = sum_j p[(k-j)&15] q[j] ----
        // tree of four 4-FMA chains per conv; rotated P consumed in place
        const float4 La = *(const float4*)&sQL[g][0];
        const float4 Lb = *(const float4*)&sQL[g][4];
        const float4 Lc = *(const float4*)&sQL[g][8];
        const float4 Ld = *(const float4*)&sQL[g][12];
        float rl = (conv_quad(pal,              fdpp<0x121>(pal), fdpp<0x122>(pal), fdpp<0x123>(pal), La)
                  + conv_quad(fdpp<0x124>(pal), fdpp<0x125>(pal), fdpp<0x126>(pal), fdpp<0x127>(pal), Lb))
                 + (conv_quad(fdpp<0x128>(pal), fdpp<0x129>(pal), fdpp<0x12A>(pal), fdpp<0x12B>(pal), Lc)
                  + conv_quad(fdpp<0x12C>(pal), fdpp<0x12D>(pal), fdpp<0x12E>(pal), fdpp<0x12F>(pal), Ld));

        const float4 Ha = *(const float4*)&sQH[g][0];
        const float4 Hb = *(const float4*)&sQH[g][4];
        const float4 Hc = *(const float4*)&sQH[g][8];
        const float4 Hd = *(const float4*)&sQH[g][12];
        float rh = (conv_quad(pah,              fdpp<0x121>(pah), fdpp<0x122>(pah), fdpp<0x123>(pah), Ha)
                  + conv_quad(fdpp<0x124>(pah), fdpp<0x125>(pah), fdpp<0x126>(pah), fdpp<0x127>(pah), Hb))
                 + (conv_quad(fdpp<0x128>(pah), fdpp<0x129>(pah), fdpp<0x12A>(pah), fdpp<0x12B>(pah), Hc)
                  + conv_quad(fdpp<0x12C>(pah), fdpp<0x12D>(pah), fdpp<0x12E>(pah), fdpp<0x12F>(pah), Hd));

        // ---- serial carry chain (tiny; redundantly computed by every lane) ----
        float pc0, pc1, qc0, qc1;
        carry_chain(*(const float4*)&sOV[w][0][0], *(const float4*)&sOV[w][1][0],
                    *(const float4*)&sOV[w][2][0], *(const float4*)&sOV[w][3][0],
                    b, pc0, pc1, qc0, qc1);

        // ---- nibble sums with carry mixing ----
        float slow  = pc0 * rl + pc1 * fdpp<0x121>(rl);   // rl[(k-1)&15]
        float shigh = qc0 * rh + qc1 * fdpp<0x121>(rh);

        // ---- n2b: out[16h + l] = psh[h] * psl[l] ----
        float psl = softmax16d(slow);
        float psh = softmax16d(shigh);
        sPSL[g][k] = psl;
        sPSH[g][k] = psh;

        // full-cache-line stores: instr c writes group's bytes [64c .. 64c+63]
        const float4 pslq = *(const float4*)&sPSL[g][4 * (k & 3)];
        float* po = O + base;
        #pragma unroll
        for (int c = 0; c < 4; ++c) {
            float hs = sPSH[g][4 * c + (k >> 2)];
            *(float4*)(po + 64 * c + 4 * k) =
                make_float4(hs * pslq.x, hs * pslq.y, hs * pslq.z, hs * pslq.w);
        }

        // ---- rotate pipeline ----
        ra0 = xa0; ra1 = xa1; ra2 = xa2; ra3 = xa3;
        rb0 = xb0; rb1 = xb1; rb2 = xb2; rb3 = xb3;
        base = nbase;
    }
}

extern "C" void kernel_launch(void* const* d_in, const int* in_sizes, int n_in,
                              void* d_out, int out_size, void* d_ws, size_t ws_size,
                              hipStream_t stream) {
    const float* A = (const float*)d_in[0];
    const float* B = (const float*)d_in[1];
    float* O = (float*)d_out;
    int nrows = in_sizes[0] / 1024;          // [B,4,256] -> B
    int grid = (nrows + 15) / 16;            // 16 rows/block: 4 waves x 4-row pipeline
    nalu_kernel<<<grid, 256, 0, stream>>>(A, B, O, nrows);
}

// Round 5
// 312.563 us; speedup vs baseline: 1.0945x; 1.0080x over previous
//
#include <hip/hip_runtime.h>

#define NIB_SCALE 100.0f

// ---- DPP helpers (16-lane "row" ops on the VALU pipe; rows == nibble groups) ----
// ctrl: 0x110+N row_shr, 0x120+N row_ror, 0x140 row_mirror
template<int CTRL>
__device__ __forceinline__ float fdpp(float x) {
    return __int_as_float(__builtin_amdgcn_update_dpp(
        0, __float_as_int(x), CTRL, 0xF, 0xF, true));
}

__device__ __forceinline__ float rsum16d(float v) {
    v += fdpp<0x121>(v); v += fdpp<0x122>(v); v += fdpp<0x124>(v); v += fdpp<0x128>(v);
    return v;
}
__device__ __forceinline__ float rmax16d(float v) {
    v = fmaxf(v, fdpp<0x121>(v)); v = fmaxf(v, fdpp<0x122>(v));
    v = fmaxf(v, fdpp<0x124>(v)); v = fmaxf(v, fdpp<0x128>(v));
    return v;
}
// inclusive ascending prefix sum within the 16-lane row
__device__ __forceinline__ float scan16d(float v) {
    v += fdpp<0x111>(v); v += fdpp<0x112>(v); v += fdpp<0x114>(v); v += fdpp<0x118>(v);
    return v;
}
__device__ __forceinline__ float softmax16d(float v) {
    float m = rmax16d(v);
    float e = __expf(NIB_SCALE * (v - m));
    float s = rsum16d(e);
    return e / s;
}
// for inputs known to lie in [0,1] with row-sum 1 (max >= 1/16): a FIXED shift
// of 0.5 keeps exponents in [-50,50] (no overflow/underflow, ratios exact) and
// removes the 8-inst DPP max chain from the critical path.
__device__ __forceinline__ float softmax16_fix(float v) {
    float e = __expf(NIB_SCALE * (v - 0.5f));
    float s = rsum16d(e);
    return e / s;
}
__device__ __forceinline__ float sharp_sigmoid(float c) {
    // softmax2(100*[1-c, c])[1] = 1/(1+exp(100*(1-2c)))
    return 1.0f / (1.0f + __expf(NIB_SCALE * (1.0f - 2.0f * c)));
}
__device__ __forceinline__ float rdlane(float x, int l) {
    return __int_as_float(__builtin_amdgcn_readlane(__float_as_int(x), l));
}

// one quarter of the circular conv: 4-FMA chain over one float4 of Q with
// in-place rotated P values (no G[] array -> shorter chains, fewer live regs)
__device__ __forceinline__ float conv_quad(float g0, float g1, float g2, float g3,
                                           const float4 q) {
    return fmaf(g0, q.x, fmaf(g1, q.y, fmaf(g2, q.z, g3 * q.w)));
}

// Full per-row tail after the four logits are known. All cross-lane traffic is
// intra-wave (DPP / readlane / LDS broadcast reads) -> no barriers.
__device__ __forceinline__ void stream_tail(float al, float bl, float ah, float bh,
                                            int k, int g, int b,
                                            float (&QL)[16][16], float (&QH)[16][16],
                                            float (&PSL)[16][16], float (&PSH)[16][16],
                                            float* __restrict__ po) {
    // factorized sharp softmaxes (exact vs the joint 512-softmax)
    float pal = softmax16d(al);
    float pbl = softmax16d(bl);
    float pah = softmax16d(ah);
    float pbh = softmax16d(bh);

    QL[g][k] = pbl;
    QH[g][k] = pbh;

    // overflow masses, pure DPP:
    // mir[k]=q[15-k]; T15[k]=sum_{v>=15-k} q[v]; ov15=sum_{a+v>=15} p[a]q[v]
    float mirl = fdpp<0x140>(pbl);
    float mirh = fdpp<0x140>(pbh);
    float T15l = scan16d(mirl);
    float T15h = scan16d(mirh);
    float ov15l = rsum16d(pal * T15l);
    float c15l  = rsum16d(pal * mirl);
    float ov15h = rsum16d(pah * T15h);
    float c15h  = rsum16d(pah * mirh);
    float ov16l = ov15l - c15l;
    float ov16h = ov15h - c15h;

    // wave-level broadcast of the per-byte carry masses via readlane (bytes
    // 0..3 live in wave-lanes 0/16/32/48) -- replaces the LDS sOV
    // write->wait->read roundtrip that sat on the serial carry path.
    float l16[4] = { rdlane(ov16l,0), rdlane(ov16l,16), rdlane(ov16l,32), rdlane(ov16l,48) };
    float l15[4] = { rdlane(ov15l,0), rdlane(ov15l,16), rdlane(ov15l,32), rdlane(ov15l,48) };
    float h16[4] = { rdlane(ov16h,0), rdlane(ov16h,16), rdlane(ov16h,32), rdlane(ov16h,48) };
    float h15[4] = { rdlane(ov15h,0), rdlane(ov15h,16), rdlane(ov15h,32), rdlane(ov15h,48) };

    // ---- circular convolutions r[k] = sum_j p[(k-j)&15] q[j] ----
    // independent of the carry chain below; scheduler interleaves the two.
    const float4 La = *(const float4*)&QL[g][0];
    const float4 Lb = *(const float4*)&QL[g][4];
    const float4 Lc = *(const float4*)&QL[g][8];
    const float4 Ld = *(const float4*)&QL[g][12];
    float rl = (conv_quad(pal,              fdpp<0x121>(pal), fdpp<0x122>(pal), fdpp<0x123>(pal), La)
              + conv_quad(fdpp<0x124>(pal), fdpp<0x125>(pal), fdpp<0x126>(pal), fdpp<0x127>(pal), Lb))
             + (conv_quad(fdpp<0x128>(pal), fdpp<0x129>(pal), fdpp<0x12A>(pal), fdpp<0x12B>(pal), Lc)
              + conv_quad(fdpp<0x12C>(pal), fdpp<0x12D>(pal), fdpp<0x12E>(pal), fdpp<0x12F>(pal), Ld));

    const float4 Ha = *(const float4*)&QH[g][0];
    const float4 Hb = *(const float4*)&QH[g][4];
    const float4 Hc = *(const float4*)&QH[g][8];
    const float4 Hd = *(const float4*)&QH[g][12];
    float rh = (conv_quad(pah,              fdpp<0x121>(pah), fdpp<0x122>(pah), fdpp<0x123>(pah), Ha)
              + conv_quad(fdpp<0x124>(pah), fdpp<0x125>(pah), fdpp<0x126>(pah), fdpp<0x127>(pah), Hb))
             + (conv_quad(fdpp<0x128>(pah), fdpp<0x129>(pah), fdpp<0x12A>(pah), fdpp<0x12B>(pah), Hc)
              + conv_quad(fdpp<0x12C>(pah), fdpp<0x12D>(pah), fdpp<0x12E>(pah), fdpp<0x12F>(pah), Hd));

    // ---- serial carry chain (tiny; redundantly computed by every lane) ----
    // byte 0: incoming pc = (1, 0)  (softmax2([1,0]*100): pc1 = 3.7e-44 ~ 0)
    float qc1_0 = sharp_sigmoid(l16[0]);
    float qc0_0 = 1.f - qc1_0;
    float pc1_1 = sharp_sigmoid(qc0_0 * h16[0] + qc1_0 * h15[0]);
    float pc0_1 = 1.f - pc1_1;
    float qc1_1 = sharp_sigmoid(pc0_1 * l16[1] + pc1_1 * l15[1]);
    float qc0_1 = 1.f - qc1_1;
    float pc1_2 = sharp_sigmoid(qc0_1 * h16[1] + qc1_1 * h15[1]);
    float pc0_2 = 1.f - pc1_2;
    float qc1_2 = sharp_sigmoid(pc0_2 * l16[2] + pc1_2 * l15[2]);
    float qc0_2 = 1.f - qc1_2;
    float pc1_3 = sharp_sigmoid(qc0_2 * h16[2] + qc1_2 * h15[2]);
    float pc0_3 = 1.f - pc1_3;
    float qc1_3 = sharp_sigmoid(pc0_3 * l16[3] + pc1_3 * l15[3]);
    float qc0_3 = 1.f - qc1_3;

    // select this group's byte position (b is group-uniform -> cheap cndmasks)
    float pc0 = b == 0 ? 1.f   : b == 1 ? pc0_1 : b == 2 ? pc0_2 : pc0_3;
    float pc1 = b == 0 ? 0.f   : b == 1 ? pc1_1 : b == 2 ? pc1_2 : pc1_3;
    float qc0 = b == 0 ? qc0_0 : b == 1 ? qc0_1 : b == 2 ? qc0_2 : qc0_3;
    float qc1 = b == 0 ? qc1_0 : b == 1 ? qc1_1 : b == 2 ? qc1_2 : qc1_3;

    // ---- nibble sums with carry mixing ----
    float slow  = pc0 * rl + pc1 * fdpp<0x121>(rl);   // rl[(k-1)&15]
    float shigh = qc0 * rh + qc1 * fdpp<0x121>(rh);

    // ---- n2b: out[16h + l] = psh[h] * psl[l] ----
    float psl = softmax16_fix(slow);
    float psh = softmax16_fix(shigh);
    PSL[g][k] = psl;
    PSH[g][k] = psh;

    // full-cache-line stores: instr c writes group's bytes [64c .. 64c+63]
    const float4 pslq = *(const float4*)&PSL[g][4 * (k & 3)];
    #pragma unroll
    for (int c = 0; c < 4; ++c) {
        float hs = PSH[g][4 * c + (k >> 2)];
        *(float4*)(po + 64 * c + 4 * k) =
            make_float4(hs * pslq.x, hs * pslq.y, hs * pslq.z, hs * pslq.w);
    }
}

// TWO rows per wave as two independent dataflow streams (r3 idea, spill-free):
// r0-r4 counters show wall-time ~ rows x per-row serial latency at effective
// concurrency ~1 -> a second in-wave stream fills the dep/stall slots.
// amdgpu_waves_per_eu(4,4) pins the compiler to the 128-VGPR budget so it
// cannot repeat r3's 64-reg+spill choice (WRITE_SIZE is the canary).
__global__ __launch_bounds__(256)
__attribute__((amdgpu_waves_per_eu(4, 4)))
void nalu_kernel(const float* __restrict__ A,
                 const float* __restrict__ B,
                 float* __restrict__ O,
                 int nrows) {
    __shared__ __align__(16) float sQL[2][16][16];
    __shared__ __align__(16) float sQH[2][16][16];
    __shared__ __align__(16) float sPSL[2][16][16];
    __shared__ __align__(16) float sPSH[2][16][16];

    const int tid = threadIdx.x;
    const int k = tid & 15;           // nibble-value lane within the 16-lane group
    const int g = tid >> 4;           // group id within block (16 groups)
    const int b = g & 3;              // byte index handled by this group
    const int w = tid >> 6;           // wave id within block
    const int row0 = blockIdx.x * 8 + w * 2;
    if (row0 >= nrows) return;        // wave-uniform
    const long base0 = (long)row0 * 1024 + b * 256;
    // tail clamp: stream 1 duplicates stream 0 (same data, same address, benign)
    const long base1 = base0 + ((row0 + 1 < nrows) ? 1024 : 0);

    const float* pa0 = A + base0;  const float* pb0 = B + base0;
    const float* pa1 = A + base1;  const float* pb1 = B + base1;

    // ---- both streams' row loads first: 16 float4 in flight ----
    const float4* qa0 = (const float4*)(pa0 + 16 * k);
    const float4* qb0 = (const float4*)(pb0 + 16 * k);
    const float4* qa1 = (const float4*)(pa1 + 16 * k);
    const float4* qb1 = (const float4*)(pb1 + 16 * k);
    float4 ra0 = qa0[0], ra1 = qa0[1], ra2 = qa0[2], ra3 = qa0[3];
    float4 rb0 = qb0[0], rb1 = qb0[1], rb2 = qb0[2], rb3 = qb0[3];
    float4 sa0 = qa1[0], sa1 = qa1[1], sa2 = qa1[2], sa3 = qa1[3];
    float4 sb0 = qb1[0], sb1 = qb1[1], sb2 = qb1[2], sb3 = qb1[3];

    // ---- s0 column loads (low-nibble logits): strided dwords, accumulated ----
    float uA0 = 0, uA1 = 0, uA2 = 0, uA3 = 0, uB0 = 0, uB1 = 0, uB2 = 0, uB3 = 0;
    #pragma unroll
    for (int e = 0; e < 4; ++e) {
        uA0 += pa0[16 * e + k];        uB0 += pb0[16 * e + k];
        uA1 += pa0[16 * (e + 4) + k];  uB1 += pb0[16 * (e + 4) + k];
        uA2 += pa0[16 * (e + 8) + k];  uB2 += pb0[16 * (e + 8) + k];
        uA3 += pa0[16 * (e + 12) + k]; uB3 += pb0[16 * (e + 12) + k];
    }

    // ---- consume s0 (frees its 32 row regs + col temps) ----
    float al0 = (uA0 + uA1) + (uA2 + uA3);
    float bl0 = (uB0 + uB1) + (uB2 + uB3);
    float ah0 = ((ra0.x + ra0.y) + (ra0.z + ra0.w)) + ((ra1.x + ra1.y) + (ra1.z + ra1.w))
              + ((ra2.x + ra2.y) + (ra2.z + ra2.w)) + ((ra3.x + ra3.y) + (ra3.z + ra3.w));
    float bh0 = ((rb0.x + rb0.y) + (rb0.z + rb0.w)) + ((rb1.x + rb1.y) + (rb1.z + rb1.w))
              + ((rb2.x + rb2.y) + (rb2.z + rb2.w)) + ((rb3.x + rb3.y) + (rb3.z + rb3.w));

    // ---- s1 column loads: issued here so their latency hides under tail0 ----
    float vA0 = 0, vA1 = 0, vA2 = 0, vA3 = 0, vB0 = 0, vB1 = 0, vB2 = 0, vB3 = 0;
    #pragma unroll
    for (int e = 0; e < 4; ++e) {
        vA0 += pa1[16 * e + k];        vB0 += pb1[16 * e + k];
        vA1 += pa1[16 * (e + 4) + k];  vB1 += pb1[16 * (e + 4) + k];
        vA2 += pa1[16 * (e + 8) + k];  vB2 += pb1[16 * (e + 8) + k];
        vA3 += pa1[16 * (e + 12) + k]; vB3 += pb1[16 * (e + 12) + k];
    }

    // pin all loads above the compute tails
    __builtin_amdgcn_sched_barrier(0);

    // ---- stream 0 tail (s1 loads landing underneath) ----
    stream_tail(al0, bl0, ah0, bh0, k, g, b, sQL[0], sQH[0], sPSL[0], sPSH[0], O + base0);

    // ---- consume s1 ----
    float al1 = (vA0 + vA1) + (vA2 + vA3);
    float bl1 = (vB0 + vB1) + (vB2 + vB3);
    float ah1 = ((sa0.x + sa0.y) + (sa0.z + sa0.w)) + ((sa1.x + sa1.y) + (sa1.z + sa1.w))
              + ((sa2.x + sa2.y) + (sa2.z + sa2.w)) + ((sa3.x + sa3.y) + (sa3.z + sa3.w));
    float bh1 = ((sb0.x + sb0.y) + (sb0.z + sb0.w)) + ((sb1.x + sb1.y) + (sb1.z + sb1.w))
              + ((sb2.x + sb2.y) + (sb2.z + sb2.w)) + ((sb3.x + sb3.y) + (sb3.z + sb3.w));

    // ---- stream 1 tail (scheduler interleaves with remnants of tail0) ----
    stream_tail(al1, bl1, ah1, bh1, k, g, b, sQL[1], sQH[1], sPSL[1], sPSH[1], O + base1);
}

extern "C" void kernel_launch(void* const* d_in, const int* in_sizes, int n_in,
                              void* d_out, int out_size, void* d_ws, size_t ws_size,
                              hipStream_t stream) {
    const float* A = (const float*)d_in[0];
    const float* B = (const float*)d_in[1];
    float* O = (float*)d_out;
    int nrows = in_sizes[0] / 1024;          // [B,4,256] -> B
    int grid = (nrows + 7) / 8;              // 8 rows per block: 4 waves x 2 streams
    nalu_kernel<<<grid, 256, 0, stream>>>(A, B, O, nrows);
}